// Round 11
// baseline (331.443 us; speedup 1.0000x reference)
//
#include <hip/hip_runtime.h>
#include <hip/hip_fp16.h>
#include <math.h>

#define N_NODES 50000
#define N_EDGES 800000
#define IN_FEATS 128
#define N_HIDDEN 64
#define OUT_FEATS 40
#define DIM 8
#define SCAN_NB ((N_NODES + 255) / 256)       // 196
#define EDGE_BLOCKS 1024
#define GT_TILES ((N_NODES + 63) / 64)        // 782 node tiles of 64

typedef _Float16 half8 __attribute__((ext_vector_type(8)));
typedef float floatx4 __attribute__((ext_vector_type(4)));

// ---------------- wave-wide inclusive scan (64 lanes) ----------------
__device__ __forceinline__ int wave_incl_scan(int x, int lane) {
#pragma unroll
    for (int off = 1; off < 64; off <<= 1) {
        int v = __shfl_up(x, off, 64);
        if (lane >= off) x += v;
    }
    return x;
}

// ============================================================================
// Combo: blocks [0, EDGE_BLOCKS) do edge pre-pass (histogram + gaussian pack);
//        blocks [EDGE_BLOCKS, +GT_TILES) do gemm1 via MFMA (h1 = X @ W1 -> fp16).
// ============================================================================
__global__ __launch_bounds__(256) void combo_kernel(
    const float* __restrict__ features, const float* __restrict__ W1,
    const int* __restrict__ src, const int* __restrict__ dst,
    const float* __restrict__ ew,
    const float* __restrict__ mu1, const float* __restrict__ is1,
    const float* __restrict__ mu2, const float* __restrict__ is2,
    int* __restrict__ counts, int2* __restrict__ tmp,
    __half* __restrict__ h1)
{
    const int tid = threadIdx.x;
    __shared__ __align__(16) __half XT[64][136];   // features tile [node][k] fp16
    __shared__ __align__(16) __half WT[64][136];   // W1 transposed [n][k]  fp16

    if (blockIdx.x < EDGE_BLOCKS) {
        // ---- edge pre-pass: in-degree histogram + packed {src, (g1,g2):half2} ----
        for (int e = blockIdx.x * 256 + tid; e < N_EDGES; e += EDGE_BLOCKS * 256) {
            atomicAdd(&counts[dst[e]], 1);
            float s1 = 0.f, s2 = 0.f;
#pragma unroll
            for (int d = 0; d < DIM; ++d) {
                float v = ew[e * DIM + d];
                float d1 = v - mu1[d]; float a1 = is1[d];
                float d2 = v - mu2[d]; float a2 = is2[d];
                s1 += d1 * d1 * a1 * a1;
                s2 += d2 * d2 * a2 * a2;
            }
            __half2 g = __floats2half2_rn(expf(-0.5f * s1), expf(-0.5f * s2));
            int2 rec;
            rec.x = src[e];
            rec.y = *reinterpret_cast<int*>(&g);
            tmp[e] = rec;
        }
        return;
    }

    // ---- gemm1 tile: 64 nodes x 64 feats per block, MFMA 16x16x32 f16 ----
    int tile = blockIdx.x - EDGE_BLOCKS;
    int nodeBase = tile * 64;

    for (int i = tid; i < 64 * 32; i += 256) {
        int row = i >> 5, c4 = i & 31;
        int n = nodeBase + row;
        float4 v = make_float4(0.f, 0.f, 0.f, 0.f);
        if (n < N_NODES) v = ((const float4*)features)[(size_t)n * 32 + c4];
        __half2 h01 = __floats2half2_rn(v.x, v.y);
        __half2 h23 = __floats2half2_rn(v.z, v.w);
        uint2 pk;
        pk.x = *reinterpret_cast<unsigned*>(&h01);
        pk.y = *reinterpret_cast<unsigned*>(&h23);
        *reinterpret_cast<uint2*>(&XT[row][c4 * 4]) = pk;
    }
    for (int rep = 0; rep < 32; ++rep) {
        int idx = tid + rep * 256;          // 0..8191 = k*64 + n
        int k = idx >> 6, n = idx & 63;
        WT[n][k] = __float2half(W1[idx]);
    }
    __syncthreads();

    int lane = tid & 63, w = tid >> 6;
    int m = lane & 15, quad = lane >> 4;

    floatx4 acc0 = {0.f,0.f,0.f,0.f}, acc1 = acc0, acc2 = acc0, acc3 = acc0;
#pragma unroll
    for (int kc = 0; kc < 4; ++kc) {
        half8 a = *(const half8*)&XT[w * 16 + m][kc * 32 + quad * 8];
        half8 b0 = *(const half8*)&WT[ 0 + m][kc * 32 + quad * 8];
        half8 b1 = *(const half8*)&WT[16 + m][kc * 32 + quad * 8];
        half8 b2 = *(const half8*)&WT[32 + m][kc * 32 + quad * 8];
        half8 b3 = *(const half8*)&WT[48 + m][kc * 32 + quad * 8];
        acc0 = __builtin_amdgcn_mfma_f32_16x16x32_f16(a, b0, acc0, 0, 0, 0);
        acc1 = __builtin_amdgcn_mfma_f32_16x16x32_f16(a, b1, acc1, 0, 0, 0);
        acc2 = __builtin_amdgcn_mfma_f32_16x16x32_f16(a, b2, acc2, 0, 0, 0);
        acc3 = __builtin_amdgcn_mfma_f32_16x16x32_f16(a, b3, acc3, 0, 0, 0);
    }
    int nodeRow = nodeBase + w * 16 + quad * 4;
#pragma unroll
    for (int r = 0; r < 4; ++r) {
        int n = nodeRow + r;
        if (n < N_NODES) {
            size_t base = (size_t)n * N_HIDDEN + m;
            h1[base +  0] = __float2half(acc0[r]);
            h1[base + 16] = __float2half(acc1[r]);
            h1[base + 32] = __float2half(acc2[r]);
            h1[base + 48] = __float2half(acc3[r]);
        }
    }
}

// ============================================================================
// Single-dispatch decoupled-lookback scan over counts -> offsets + cursor.
// ============================================================================
__global__ __launch_bounds__(256) void scan_kernel(const int* __restrict__ counts,
                                                   int* __restrict__ offsets,
                                                   int* __restrict__ cursor,
                                                   int* __restrict__ partials) {
    const int tid = threadIdx.x, bid = blockIdx.x;
    int i = bid * 256 + tid;
    int lane = tid & 63, wid = tid >> 6;
    int x = (i < N_NODES) ? counts[i] : 0;
    int incl = wave_incl_scan(x, lane);
    __shared__ int wsum[4];
    __shared__ int sExc, sTot;
    if (lane == 63) wsum[wid] = incl;
    __syncthreads();
    int base = 0;
#pragma unroll
    for (int w = 0; w < 4; ++w)
        if (w < wid) base += wsum[w];
    int lexcl = base + incl - x;
    if (tid == 255) sTot = base + incl;
    __syncthreads();
    if (tid == 0) {
        int T = sTot;
        if (bid == 0) {
            __hip_atomic_store(&partials[0], (T << 2) | 2,
                               __ATOMIC_RELAXED, __HIP_MEMORY_SCOPE_AGENT);
            sExc = 0;
        } else {
            __hip_atomic_store(&partials[bid], (T << 2) | 1,
                               __ATOMIC_RELAXED, __HIP_MEMORY_SCOPE_AGENT);
            int sum = 0, pb = bid - 1;
            while (true) {
                int v = __hip_atomic_load(&partials[pb],
                                          __ATOMIC_RELAXED, __HIP_MEMORY_SCOPE_AGENT);
                if (v == 0) continue;
                sum += v >> 2;
                if ((v & 3) == 2) break;
                --pb;
            }
            __hip_atomic_store(&partials[bid], ((sum + T) << 2) | 2,
                               __ATOMIC_RELAXED, __HIP_MEMORY_SCOPE_AGENT);
            sExc = sum;
        }
    }
    __syncthreads();
    int E = sExc;
    if (i < N_NODES) {
        int v = E + lexcl;
        offsets[i] = v;
        cursor[i]  = v;
    }
    if (bid == SCAN_NB - 1 && tid == 0) offsets[N_NODES] = N_EDGES;
}

// ---------------- fill: scatter packed records into dst-CSR slots ----------------
__global__ void fill_kernel(const int* __restrict__ dst, const int2* __restrict__ tmp,
                            int* __restrict__ cursor, int2* __restrict__ csr) {
    int e = blockIdx.x * blockDim.x + threadIdx.x;
    if (e >= N_EDGES) return;
    int pos = atomicAdd(&cursor[dst[e]], 1);
    csr[pos] = tmp[e];
}

// ---------------- agg1 + gemm2 fused: batched-gather version ----------------
// Wave = 1 node; lanes 0..15 load 16 csr records in ONE coalesced instr,
// shfl-broadcast, then all 16 h1-gathers issue in flight (2 round trips/chunk).
__global__ __launch_bounds__(256) void agg1_gemm2_kernel(const __half* __restrict__ h,
                                                         const int* __restrict__ offsets,
                                                         const int2* __restrict__ csr,
                                                         const float* __restrict__ b,
                                                         const float* __restrict__ W2,
                                                         __half* __restrict__ h2) {
    __shared__ float xs[4 * N_HIDDEN];
    int wid = threadIdx.x >> 6;
    int t   = threadIdx.x & 63;
    int n   = blockIdx.x * 4 + wid;
    int beg = offsets[n], end = offsets[n + 1];
    float acc = 0.f;
    for (int base = beg; base < end; base += 16) {
        int cnt = end - base; if (cnt > 16) cnt = 16;     // wave-uniform
        int idx = base + (t & 15);
        int2 rec = csr[idx < end ? idx : end - 1];
        float vv[16], gg[16];
#pragma unroll
        for (int j = 0; j < 16; ++j) {
            int s  = __shfl(rec.x, j, 64);
            int gb = __shfl(rec.y, j, 64);
            gg[j] = __low2float(*reinterpret_cast<__half2*>(&gb));
            vv[j] = (j < cnt) ? __half2float(h[(size_t)s * N_HIDDEN + t]) : 0.f;
        }
#pragma unroll
        for (int j = 0; j < 16; ++j)
            acc += vv[j] * gg[j];
    }
    float x = acc + b[t];
    xs[wid * N_HIDDEN + t] = x;   // wave-private region: no barrier needed
    if (t < OUT_FEATS) {
        const float* xr = &xs[wid * N_HIDDEN];
        float a2 = 0.f;
#pragma unroll
        for (int k = 0; k < N_HIDDEN; ++k)
            a2 += xr[k] * W2[k * OUT_FEATS + t];
        h2[(size_t)n * OUT_FEATS + t] = __float2half(a2);
    }
}

// ---------------- agg layer 2 + b2 + log_softmax fused (batched-gather) ----------------
__global__ __launch_bounds__(256) void agg2_kernel(const __half* __restrict__ h,
                                                   const int* __restrict__ offsets,
                                                   const int2* __restrict__ csr,
                                                   const float* __restrict__ b,
                                                   float* __restrict__ out) {
    int n = blockIdx.x * 4 + (threadIdx.x >> 6);
    int t = threadIdx.x & 63;
    if (n >= N_NODES) return;
    int tc = (t < OUT_FEATS) ? t : (OUT_FEATS - 1);   // clamp: no divergence, no OOB
    int beg = offsets[n], end = offsets[n + 1];
    float acc = 0.f;
    for (int base = beg; base < end; base += 16) {
        int cnt = end - base; if (cnt > 16) cnt = 16;
        int idx = base + (t & 15);
        int2 rec = csr[idx < end ? idx : end - 1];
        float vv[16], gg[16];
#pragma unroll
        for (int j = 0; j < 16; ++j) {
            int s  = __shfl(rec.x, j, 64);
            int gb = __shfl(rec.y, j, 64);
            gg[j] = __high2float(*reinterpret_cast<__half2*>(&gb));
            vv[j] = (j < cnt) ? __half2float(h[(size_t)s * OUT_FEATS + tc]) : 0.f;
        }
#pragma unroll
        for (int j = 0; j < 16; ++j)
            acc += vv[j] * gg[j];
    }

    float v = (t < OUT_FEATS) ? acc + b[t] : -INFINITY;
    float m = v;
#pragma unroll
    for (int off = 32; off; off >>= 1)
        m = fmaxf(m, __shfl_xor(m, off, 64));
    float ex = (t < OUT_FEATS) ? expf(v - m) : 0.f;
    float s = ex;
#pragma unroll
    for (int off = 32; off; off >>= 1)
        s += __shfl_xor(s, off, 64);
    if (t < OUT_FEATS)
        out[n * OUT_FEATS + t] = v - m - logf(s);
}

extern "C" void kernel_launch(void* const* d_in, const int* in_sizes, int n_in,
                              void* d_out, int out_size, void* d_ws, size_t ws_size,
                              hipStream_t stream) {
    const float* features    = (const float*)d_in[0];
    const float* edge_weight = (const float*)d_in[1];
    const int*   src         = (const int*)d_in[2];
    const int*   dst         = (const int*)d_in[3];
    const float* W1          = (const float*)d_in[4];
    const float* b1          = (const float*)d_in[5];
    const float* mu1         = (const float*)d_in[6];
    const float* is1         = (const float*)d_in[7];
    const float* W2          = (const float*)d_in[8];
    const float* b2          = (const float*)d_in[9];
    const float* mu2         = (const float*)d_in[10];
    const float* is2         = (const float*)d_in[11];
    float* out = (float*)d_out;

    // Workspace: csr int2[800k] | tmp int2[800k] | h1 half[3.2M] | h2 half[2M]
    //            | counts[50k] | partials[256] | cursor[50k] | offsets[50k+1]
    int2*   csr     = (int2*)d_ws;
    int2*   tmp     = csr + N_EDGES;
    __half* h1      = (__half*)(tmp + N_EDGES);
    __half* h2      = h1 + (size_t)N_NODES * N_HIDDEN;
    int*    counts  = (int*)(h2 + (size_t)N_NODES * OUT_FEATS);
    int*    partials= counts + N_NODES;          // 256 slots (196 used)
    int*    cursor  = partials + 256;
    int*    offsets = cursor + N_NODES;

    hipMemsetAsync(counts, 0, (N_NODES + 256) * sizeof(int), stream);

    combo_kernel<<<EDGE_BLOCKS + GT_TILES, 256, 0, stream>>>(
        features, W1, src, dst, edge_weight, mu1, is1, mu2, is2, counts, tmp, h1);

    scan_kernel<<<SCAN_NB, 256, 0, stream>>>(counts, offsets, cursor, partials);

    fill_kernel<<<(N_EDGES + 255) / 256, 256, 0, stream>>>(dst, tmp, cursor, csr);

    agg1_gemm2_kernel<<<N_NODES / 4, 256, 0, stream>>>(h1, offsets, csr, b1, W2, h2);

    agg2_kernel<<<(N_NODES + 3) / 4, 256, 0, stream>>>(h2, offsets, csr, b2, out);
}

// Round 12
// 269.821 us; speedup vs baseline: 1.2284x; 1.2284x over previous
//
#include <hip/hip_runtime.h>
#include <hip/hip_fp16.h>
#include <math.h>

#define N_NODES 50000
#define N_EDGES 800000
#define IN_FEATS 128
#define N_HIDDEN 64
#define OUT_FEATS 40
#define DIM 8
#define SCAN_NB ((N_NODES + 255) / 256)       // 196
#define EDGE_BLOCKS 1024
#define GT_TILES ((N_NODES + 63) / 64)        // 782 node tiles of 64

typedef _Float16 half8 __attribute__((ext_vector_type(8)));
typedef float floatx4 __attribute__((ext_vector_type(4)));

// ---------------- wave-wide inclusive scan (64 lanes) ----------------
__device__ __forceinline__ int wave_incl_scan(int x, int lane) {
#pragma unroll
    for (int off = 1; off < 64; off <<= 1) {
        int v = __shfl_up(x, off, 64);
        if (lane >= off) x += v;
    }
    return x;
}

// ============================================================================
// Combo: blocks [0, EDGE_BLOCKS) do edge pre-pass (histogram + gaussian pack);
//        blocks [EDGE_BLOCKS, +GT_TILES) do gemm1 via MFMA (h1 = X @ W1 -> fp16).
// ============================================================================
__global__ __launch_bounds__(256) void combo_kernel(
    const float* __restrict__ features, const float* __restrict__ W1,
    const int* __restrict__ src, const int* __restrict__ dst,
    const float* __restrict__ ew,
    const float* __restrict__ mu1, const float* __restrict__ is1,
    const float* __restrict__ mu2, const float* __restrict__ is2,
    int* __restrict__ counts, int2* __restrict__ tmp,
    __half* __restrict__ h1)
{
    const int tid = threadIdx.x;
    __shared__ __align__(16) __half XT[64][136];   // features tile [node][k] fp16
    __shared__ __align__(16) __half WT[64][136];   // W1 transposed [n][k]  fp16

    if (blockIdx.x < EDGE_BLOCKS) {
        // ---- edge pre-pass: in-degree histogram + packed {src, (g1,g2):half2} ----
        for (int e = blockIdx.x * 256 + tid; e < N_EDGES; e += EDGE_BLOCKS * 256) {
            atomicAdd(&counts[dst[e]], 1);
            float s1 = 0.f, s2 = 0.f;
#pragma unroll
            for (int d = 0; d < DIM; ++d) {
                float v = ew[e * DIM + d];
                float d1 = v - mu1[d]; float a1 = is1[d];
                float d2 = v - mu2[d]; float a2 = is2[d];
                s1 += d1 * d1 * a1 * a1;
                s2 += d2 * d2 * a2 * a2;
            }
            __half2 g = __floats2half2_rn(expf(-0.5f * s1), expf(-0.5f * s2));
            int2 rec;
            rec.x = src[e];
            rec.y = *reinterpret_cast<int*>(&g);
            tmp[e] = rec;
        }
        return;
    }

    // ---- gemm1 tile: 64 nodes x 64 feats per block, MFMA 16x16x32 f16 ----
    int tile = blockIdx.x - EDGE_BLOCKS;
    int nodeBase = tile * 64;

    for (int i = tid; i < 64 * 32; i += 256) {
        int row = i >> 5, c4 = i & 31;
        int n = nodeBase + row;
        float4 v = make_float4(0.f, 0.f, 0.f, 0.f);
        if (n < N_NODES) v = ((const float4*)features)[(size_t)n * 32 + c4];
        __half2 h01 = __floats2half2_rn(v.x, v.y);
        __half2 h23 = __floats2half2_rn(v.z, v.w);
        uint2 pk;
        pk.x = *reinterpret_cast<unsigned*>(&h01);
        pk.y = *reinterpret_cast<unsigned*>(&h23);
        *reinterpret_cast<uint2*>(&XT[row][c4 * 4]) = pk;
    }
    for (int rep = 0; rep < 32; ++rep) {
        int idx = tid + rep * 256;          // 0..8191 = k*64 + n
        int k = idx >> 6, n = idx & 63;
        WT[n][k] = __float2half(W1[idx]);
    }
    __syncthreads();

    int lane = tid & 63, w = tid >> 6;
    int m = lane & 15, quad = lane >> 4;

    floatx4 acc0 = {0.f,0.f,0.f,0.f}, acc1 = acc0, acc2 = acc0, acc3 = acc0;
#pragma unroll
    for (int kc = 0; kc < 4; ++kc) {
        half8 a = *(const half8*)&XT[w * 16 + m][kc * 32 + quad * 8];
        half8 b0 = *(const half8*)&WT[ 0 + m][kc * 32 + quad * 8];
        half8 b1 = *(const half8*)&WT[16 + m][kc * 32 + quad * 8];
        half8 b2 = *(const half8*)&WT[32 + m][kc * 32 + quad * 8];
        half8 b3 = *(const half8*)&WT[48 + m][kc * 32 + quad * 8];
        acc0 = __builtin_amdgcn_mfma_f32_16x16x32_f16(a, b0, acc0, 0, 0, 0);
        acc1 = __builtin_amdgcn_mfma_f32_16x16x32_f16(a, b1, acc1, 0, 0, 0);
        acc2 = __builtin_amdgcn_mfma_f32_16x16x32_f16(a, b2, acc2, 0, 0, 0);
        acc3 = __builtin_amdgcn_mfma_f32_16x16x32_f16(a, b3, acc3, 0, 0, 0);
    }
    int nodeRow = nodeBase + w * 16 + quad * 4;
#pragma unroll
    for (int r = 0; r < 4; ++r) {
        int n = nodeRow + r;
        if (n < N_NODES) {
            size_t base = (size_t)n * N_HIDDEN + m;
            h1[base +  0] = __float2half(acc0[r]);
            h1[base + 16] = __float2half(acc1[r]);
            h1[base + 32] = __float2half(acc2[r]);
            h1[base + 48] = __float2half(acc3[r]);
        }
    }
}

// ============================================================================
// Single-dispatch decoupled-lookback scan over counts -> offsets + cursor.
// ============================================================================
__global__ __launch_bounds__(256) void scan_kernel(const int* __restrict__ counts,
                                                   int* __restrict__ offsets,
                                                   int* __restrict__ cursor,
                                                   int* __restrict__ partials) {
    const int tid = threadIdx.x, bid = blockIdx.x;
    int i = bid * 256 + tid;
    int lane = tid & 63, wid = tid >> 6;
    int x = (i < N_NODES) ? counts[i] : 0;
    int incl = wave_incl_scan(x, lane);
    __shared__ int wsum[4];
    __shared__ int sExc, sTot;
    if (lane == 63) wsum[wid] = incl;
    __syncthreads();
    int base = 0;
#pragma unroll
    for (int w = 0; w < 4; ++w)
        if (w < wid) base += wsum[w];
    int lexcl = base + incl - x;
    if (tid == 255) sTot = base + incl;
    __syncthreads();
    if (tid == 0) {
        int T = sTot;
        if (bid == 0) {
            __hip_atomic_store(&partials[0], (T << 2) | 2,
                               __ATOMIC_RELAXED, __HIP_MEMORY_SCOPE_AGENT);
            sExc = 0;
        } else {
            __hip_atomic_store(&partials[bid], (T << 2) | 1,
                               __ATOMIC_RELAXED, __HIP_MEMORY_SCOPE_AGENT);
            int sum = 0, pb = bid - 1;
            while (true) {
                int v = __hip_atomic_load(&partials[pb],
                                          __ATOMIC_RELAXED, __HIP_MEMORY_SCOPE_AGENT);
                if (v == 0) continue;
                sum += v >> 2;
                if ((v & 3) == 2) break;
                --pb;
            }
            __hip_atomic_store(&partials[bid], ((sum + T) << 2) | 2,
                               __ATOMIC_RELAXED, __HIP_MEMORY_SCOPE_AGENT);
            sExc = sum;
        }
    }
    __syncthreads();
    int E = sExc;
    if (i < N_NODES) {
        int v = E + lexcl;
        offsets[i] = v;
        cursor[i]  = v;
    }
    if (bid == SCAN_NB - 1 && tid == 0) offsets[N_NODES] = N_EDGES;
}

// ---------------- fill: scatter packed records into dst-CSR slots ----------------
__global__ void fill_kernel(const int* __restrict__ dst, const int2* __restrict__ tmp,
                            int* __restrict__ cursor, int2* __restrict__ csr) {
    int e = blockIdx.x * blockDim.x + threadIdx.x;
    if (e >= N_EDGES) return;
    int pos = atomicAdd(&cursor[dst[e]], 1);
    csr[pos] = tmp[e];
}

// ---------------- agg1 + gemm2 fused: 2 nodes per wave, packed fp16 pairs ----------
// Block = 8 nodes (4 waves x 2). Lane: half = lane>>5 picks node, p = lane&31 picks
// feat pair. One dword gather serves 2 feats x 2 edges (one per half) per instr.
__global__ __launch_bounds__(256) void agg1_gemm2_kernel(const __half* __restrict__ h,
                                                         const int* __restrict__ offsets,
                                                         const int2* __restrict__ csr,
                                                         const float* __restrict__ b,
                                                         const float* __restrict__ W2,
                                                         __half* __restrict__ h2) {
    __shared__ float xs[8][64];
    const unsigned* h32 = (const unsigned*)h;   // h1 row = 32 dwords
    const int tid = threadIdx.x;
    const int w = tid >> 6, lane = tid & 63;
    const int hf = lane >> 5, p = lane & 31;
    const int ln = w * 2 + hf;                  // local node 0..7
    const int n = blockIdx.x * 8 + ln;
    int beg = offsets[n], end = offsets[n + 1];

    float ax = 0.f, ay = 0.f;
    int j = beg;
    for (; j + 4 <= end; j += 4) {
        int2 r0 = csr[j + 0], r1 = csr[j + 1], r2 = csr[j + 2], r3 = csr[j + 3];
        unsigned v0 = h32[(size_t)r0.x * 32 + p];
        unsigned v1 = h32[(size_t)r1.x * 32 + p];
        unsigned v2 = h32[(size_t)r2.x * 32 + p];
        unsigned v3 = h32[(size_t)r3.x * 32 + p];
        float g0 = __low2float(*reinterpret_cast<__half2*>(&r0.y));
        float g1 = __low2float(*reinterpret_cast<__half2*>(&r1.y));
        float g2 = __low2float(*reinterpret_cast<__half2*>(&r2.y));
        float g3 = __low2float(*reinterpret_cast<__half2*>(&r3.y));
        float2 f0 = __half22float2(*reinterpret_cast<__half2*>(&v0));
        float2 f1 = __half22float2(*reinterpret_cast<__half2*>(&v1));
        float2 f2 = __half22float2(*reinterpret_cast<__half2*>(&v2));
        float2 f3 = __half22float2(*reinterpret_cast<__half2*>(&v3));
        ax += f0.x * g0; ay += f0.y * g0;
        ax += f1.x * g1; ay += f1.y * g1;
        ax += f2.x * g2; ay += f2.y * g2;
        ax += f3.x * g3; ay += f3.y * g3;
    }
    for (; j < end; ++j) {
        int2 r = csr[j];
        unsigned v = h32[(size_t)r.x * 32 + p];
        float g = __low2float(*reinterpret_cast<__half2*>(&r.y));
        float2 f = __half22float2(*reinterpret_cast<__half2*>(&v));
        ax += f.x * g; ay += f.y * g;
    }
    float2 bb = *(const float2*)&b[2 * p];
    *(float2*)&xs[ln][2 * p] = make_float2(ax + bb.x, ay + bb.y);
    __syncthreads();

    // gemm2: 8 nodes x 40 outs = 320 outputs over 256 threads
    for (int o = tid; o < 8 * OUT_FEATS; o += 256) {
        int node = o / OUT_FEATS, t = o % OUT_FEATS;
        const float* xr = xs[node];
        float acc = 0.f;
#pragma unroll
        for (int k = 0; k < N_HIDDEN; ++k)
            acc += xr[k] * W2[k * OUT_FEATS + t];
        h2[(size_t)(blockIdx.x * 8 + node) * OUT_FEATS + t] = __float2half(acc);
    }
}

// ---------------- agg layer 2 + b2 + log_softmax: 2 nodes per wave ----------------
// h2 row = 40 fp16 = 20 dwords; p<20 active per half; width-32 shuffles reduce halves.
__global__ __launch_bounds__(256) void agg2_kernel(const __half* __restrict__ h,
                                                   const int* __restrict__ offsets,
                                                   const int2* __restrict__ csr,
                                                   const float* __restrict__ b,
                                                   float* __restrict__ out) {
    const unsigned* h32 = (const unsigned*)h;   // h2 row = 20 dwords
    const int tid = threadIdx.x;
    const int w = tid >> 6, lane = tid & 63;
    const int hf = lane >> 5, p = lane & 31;
    const int n = blockIdx.x * 8 + w * 2 + hf;
    const int pc = (p < 20) ? p : 19;           // clamp: no divergence, no OOB
    int beg = offsets[n], end = offsets[n + 1];

    float ax = 0.f, ay = 0.f;
    int j = beg;
    for (; j + 4 <= end; j += 4) {
        int2 r0 = csr[j + 0], r1 = csr[j + 1], r2 = csr[j + 2], r3 = csr[j + 3];
        unsigned v0 = h32[(size_t)r0.x * 20 + pc];
        unsigned v1 = h32[(size_t)r1.x * 20 + pc];
        unsigned v2 = h32[(size_t)r2.x * 20 + pc];
        unsigned v3 = h32[(size_t)r3.x * 20 + pc];
        float g0 = __high2float(*reinterpret_cast<__half2*>(&r0.y));
        float g1 = __high2float(*reinterpret_cast<__half2*>(&r1.y));
        float g2 = __high2float(*reinterpret_cast<__half2*>(&r2.y));
        float g3 = __high2float(*reinterpret_cast<__half2*>(&r3.y));
        float2 f0 = __half22float2(*reinterpret_cast<__half2*>(&v0));
        float2 f1 = __half22float2(*reinterpret_cast<__half2*>(&v1));
        float2 f2 = __half22float2(*reinterpret_cast<__half2*>(&v2));
        float2 f3 = __half22float2(*reinterpret_cast<__half2*>(&v3));
        ax += f0.x * g0; ay += f0.y * g0;
        ax += f1.x * g1; ay += f1.y * g1;
        ax += f2.x * g2; ay += f2.y * g2;
        ax += f3.x * g3; ay += f3.y * g3;
    }
    for (; j < end; ++j) {
        int2 r = csr[j];
        unsigned v = h32[(size_t)r.x * 20 + pc];
        float g = __high2float(*reinterpret_cast<__half2*>(&r.y));
        float2 f = __half22float2(*reinterpret_cast<__half2*>(&v));
        ax += f.x * g; ay += f.y * g;
    }

    bool valid = (p < 20);
    float vx = valid ? ax + b[2 * p]     : -INFINITY;
    float vy = valid ? ay + b[2 * p + 1] : -INFINITY;
    float m = fmaxf(vx, vy);
#pragma unroll
    for (int off = 16; off; off >>= 1)
        m = fmaxf(m, __shfl_xor(m, off, 32));   // reduce within each 32-lane half
    float ex = valid ? (expf(vx - m) + expf(vy - m)) : 0.f;
#pragma unroll
    for (int off = 16; off; off >>= 1)
        ex += __shfl_xor(ex, off, 32);
    float ls = logf(ex);
    if (valid) {
        float2 o = make_float2(vx - m - ls, vy - m - ls);
        *(float2*)&out[(size_t)n * OUT_FEATS + 2 * p] = o;
    }
}

extern "C" void kernel_launch(void* const* d_in, const int* in_sizes, int n_in,
                              void* d_out, int out_size, void* d_ws, size_t ws_size,
                              hipStream_t stream) {
    const float* features    = (const float*)d_in[0];
    const float* edge_weight = (const float*)d_in[1];
    const int*   src         = (const int*)d_in[2];
    const int*   dst         = (const int*)d_in[3];
    const float* W1          = (const float*)d_in[4];
    const float* b1          = (const float*)d_in[5];
    const float* mu1         = (const float*)d_in[6];
    const float* is1         = (const float*)d_in[7];
    const float* W2          = (const float*)d_in[8];
    const float* b2          = (const float*)d_in[9];
    const float* mu2         = (const float*)d_in[10];
    const float* is2         = (const float*)d_in[11];
    float* out = (float*)d_out;

    // Workspace: csr int2[800k] | tmp int2[800k] | h1 half[3.2M] | h2 half[2M]
    //            | counts[50k] | partials[256] | cursor[50k] | offsets[50k+1]
    int2*   csr     = (int2*)d_ws;
    int2*   tmp     = csr + N_EDGES;
    __half* h1      = (__half*)(tmp + N_EDGES);
    __half* h2      = h1 + (size_t)N_NODES * N_HIDDEN;
    int*    counts  = (int*)(h2 + (size_t)N_NODES * OUT_FEATS);
    int*    partials= counts + N_NODES;          // 256 slots (196 used)
    int*    cursor  = partials + 256;
    int*    offsets = cursor + N_NODES;

    hipMemsetAsync(counts, 0, (N_NODES + 256) * sizeof(int), stream);

    combo_kernel<<<EDGE_BLOCKS + GT_TILES, 256, 0, stream>>>(
        features, W1, src, dst, edge_weight, mu1, is1, mu2, is2, counts, tmp, h1);

    scan_kernel<<<SCAN_NB, 256, 0, stream>>>(counts, offsets, cursor, partials);

    fill_kernel<<<(N_EDGES + 255) / 256, 256, 0, stream>>>(dst, tmp, cursor, csr);

    agg1_gemm2_kernel<<<N_NODES / 8, 256, 0, stream>>>(h1, offsets, csr, b1, W2, h2);

    agg2_kernel<<<N_NODES / 8, 256, 0, stream>>>(h2, offsets, csr, b2, out);
}

// Round 13
// 268.881 us; speedup vs baseline: 1.2327x; 1.0035x over previous
//
#include <hip/hip_runtime.h>
#include <hip/hip_fp16.h>
#include <math.h>

#define N_NODES 50000
#define N_EDGES 800000
#define IN_FEATS 128
#define N_HIDDEN 64
#define OUT_FEATS 40
#define DIM 8
#define SCAN_NB ((N_NODES + 255) / 256)       // 196
#define GT_TILES ((N_NODES + 63) / 64)        // 782 gemm tiles
#define FILL_NB 1024

typedef _Float16 half8 __attribute__((ext_vector_type(8)));
typedef float floatx4 __attribute__((ext_vector_type(4)));

// ---------------- wave-wide inclusive scan (64 lanes) ----------------
__device__ __forceinline__ int wave_incl_scan(int x, int lane) {
#pragma unroll
    for (int off = 1; off < 64; off <<= 1) {
        int v = __shfl_up(x, off, 64);
        if (lane >= off) x += v;
    }
    return x;
}

// ============================================================================
// K1: edge pre-pass — histogram + gaussian + packed tmp record. No LDS.
// ============================================================================
__global__ __launch_bounds__(256) void edge_kernel(
    const int* __restrict__ src, const int* __restrict__ dst,
    const float* __restrict__ ew,
    const float* __restrict__ mu1, const float* __restrict__ is1,
    const float* __restrict__ mu2, const float* __restrict__ is2,
    int* __restrict__ counts, int2* __restrict__ tmp)
{
    int e = blockIdx.x * 256 + threadIdx.x;
    if (e >= N_EDGES) return;
    atomicAdd(&counts[dst[e]], 1);
    float s1 = 0.f, s2 = 0.f;
#pragma unroll
    for (int d = 0; d < DIM; ++d) {
        float v = ew[e * DIM + d];
        float d1 = v - mu1[d]; float a1 = is1[d];
        float d2 = v - mu2[d]; float a2 = is2[d];
        s1 += d1 * d1 * a1 * a1;
        s2 += d2 * d2 * a2 * a2;
    }
    __half2 g = __floats2half2_rn(expf(-0.5f * s1), expf(-0.5f * s2));
    int2 rec;
    rec.x = src[e];
    rec.y = *reinterpret_cast<int*>(&g);
    tmp[e] = rec;
}

// ============================================================================
// K2: single-dispatch decoupled-lookback scan: counts -> offsets + cursor.
// ============================================================================
__global__ __launch_bounds__(256) void scan_kernel(const int* __restrict__ counts,
                                                   int* __restrict__ offsets,
                                                   int* __restrict__ cursor,
                                                   int* __restrict__ partials) {
    const int tid = threadIdx.x, bid = blockIdx.x;
    int i = bid * 256 + tid;
    int lane = tid & 63, wid = tid >> 6;
    int x = (i < N_NODES) ? counts[i] : 0;
    int incl = wave_incl_scan(x, lane);
    __shared__ int wsum[4];
    __shared__ int sExc, sTot;
    if (lane == 63) wsum[wid] = incl;
    __syncthreads();
    int base = 0;
#pragma unroll
    for (int w = 0; w < 4; ++w)
        if (w < wid) base += wsum[w];
    int lexcl = base + incl - x;
    if (tid == 255) sTot = base + incl;
    __syncthreads();
    if (tid == 0) {
        int T = sTot;
        if (bid == 0) {
            __hip_atomic_store(&partials[0], (T << 2) | 2,
                               __ATOMIC_RELAXED, __HIP_MEMORY_SCOPE_AGENT);
            sExc = 0;
        } else {
            __hip_atomic_store(&partials[bid], (T << 2) | 1,
                               __ATOMIC_RELAXED, __HIP_MEMORY_SCOPE_AGENT);
            int sum = 0, pb = bid - 1;
            while (true) {
                int v = __hip_atomic_load(&partials[pb],
                                          __ATOMIC_RELAXED, __HIP_MEMORY_SCOPE_AGENT);
                if (v == 0) continue;
                sum += v >> 2;
                if ((v & 3) == 2) break;
                --pb;
            }
            __hip_atomic_store(&partials[bid], ((sum + T) << 2) | 2,
                               __ATOMIC_RELAXED, __HIP_MEMORY_SCOPE_AGENT);
            sExc = sum;
        }
    }
    __syncthreads();
    int E = sExc;
    if (i < N_NODES) {
        int v = E + lexcl;
        offsets[i] = v;
        cursor[i]  = v;
    }
    if (bid == SCAN_NB - 1 && tid == 0) offsets[N_NODES] = N_EDGES;
}

// ============================================================================
// K3: gemm1 tiles (blocks 0..GT_TILES) + CSR fill (remaining blocks), fused so
// the MFMA tiles hide under the scatter's write-latency. Only WT in LDS.
// ============================================================================
__global__ __launch_bounds__(256) void fillgemm_kernel(
    const float* __restrict__ features, const float* __restrict__ W1,
    const int* __restrict__ dst, const int2* __restrict__ tmp,
    int* __restrict__ cursor, int2* __restrict__ csr,
    __half* __restrict__ h1)
{
    const int tid = threadIdx.x;
    __shared__ __align__(16) __half WT[64][136];   // W1^T fp16, 17.4 KB

    if (blockIdx.x >= GT_TILES) {
        // ---- fill half: scatter packed records into dst-CSR slots ----
        int fb = blockIdx.x - GT_TILES;
        for (int e = fb * 256 + tid; e < N_EDGES; e += FILL_NB * 256) {
            int pos = atomicAdd(&cursor[dst[e]], 1);
            csr[pos] = tmp[e];
        }
        return;
    }

    // ---- gemm1 tile: 64 nodes x 64 feats, MFMA 16x16x32 f16, A from global ----
    int nodeBase = blockIdx.x * 64;
    for (int rep = 0; rep < 32; ++rep) {
        int idx = tid + rep * 256;          // 0..8191 = k*64 + n
        int k = idx >> 6, n = idx & 63;
        WT[n][k] = __float2half(W1[idx]);
    }
    __syncthreads();

    int lane = tid & 63, w = tid >> 6;
    int m = lane & 15, quad = lane >> 4;
    int row = nodeBase + w * 16 + m;
    int rowc = (row < N_NODES) ? row : (N_NODES - 1);
    const float* fr = features + (size_t)rowc * IN_FEATS;

    floatx4 acc0 = {0.f,0.f,0.f,0.f}, acc1 = acc0, acc2 = acc0, acc3 = acc0;
#pragma unroll
    for (int kc = 0; kc < 4; ++kc) {
        float4 fa = *(const float4*)(fr + kc * 32 + quad * 8);
        float4 fb = *(const float4*)(fr + kc * 32 + quad * 8 + 4);
        union { half8 v; __half2 h2[4]; } A;
        A.h2[0] = __floats2half2_rn(fa.x, fa.y);
        A.h2[1] = __floats2half2_rn(fa.z, fa.w);
        A.h2[2] = __floats2half2_rn(fb.x, fb.y);
        A.h2[3] = __floats2half2_rn(fb.z, fb.w);
        half8 b0 = *(const half8*)&WT[ 0 + m][kc * 32 + quad * 8];
        half8 b1 = *(const half8*)&WT[16 + m][kc * 32 + quad * 8];
        half8 b2 = *(const half8*)&WT[32 + m][kc * 32 + quad * 8];
        half8 b3 = *(const half8*)&WT[48 + m][kc * 32 + quad * 8];
        acc0 = __builtin_amdgcn_mfma_f32_16x16x32_f16(A.v, b0, acc0, 0, 0, 0);
        acc1 = __builtin_amdgcn_mfma_f32_16x16x32_f16(A.v, b1, acc1, 0, 0, 0);
        acc2 = __builtin_amdgcn_mfma_f32_16x16x32_f16(A.v, b2, acc2, 0, 0, 0);
        acc3 = __builtin_amdgcn_mfma_f32_16x16x32_f16(A.v, b3, acc3, 0, 0, 0);
    }
    // D layout: col = lane&15 = m (feat), row-in-tile = quad*4 + reg (node)
    int nodeRow = nodeBase + w * 16 + quad * 4;
#pragma unroll
    for (int r = 0; r < 4; ++r) {
        int n = nodeRow + r;
        if (n < N_NODES) {
            size_t base = (size_t)n * N_HIDDEN + m;
            h1[base +  0] = __float2half(acc0[r]);
            h1[base + 16] = __float2half(acc1[r]);
            h1[base + 32] = __float2half(acc2[r]);
            h1[base + 48] = __float2half(acc3[r]);
        }
    }
}

// ---------------- agg1 + gemm2 fused: 2 nodes per wave, packed fp16 pairs ----------
__global__ __launch_bounds__(256) void agg1_gemm2_kernel(const __half* __restrict__ h,
                                                         const int* __restrict__ offsets,
                                                         const int2* __restrict__ csr,
                                                         const float* __restrict__ b,
                                                         const float* __restrict__ W2,
                                                         __half* __restrict__ h2) {
    __shared__ float xs[8][64];
    const unsigned* h32 = (const unsigned*)h;   // h1 row = 32 dwords
    const int tid = threadIdx.x;
    const int w = tid >> 6, lane = tid & 63;
    const int hf = lane >> 5, p = lane & 31;
    const int ln = w * 2 + hf;                  // local node 0..7
    const int n = blockIdx.x * 8 + ln;
    int beg = offsets[n], end = offsets[n + 1];

    float ax = 0.f, ay = 0.f;
    int j = beg;
    for (; j + 4 <= end; j += 4) {
        int2 r0 = csr[j + 0], r1 = csr[j + 1], r2 = csr[j + 2], r3 = csr[j + 3];
        unsigned v0 = h32[(size_t)r0.x * 32 + p];
        unsigned v1 = h32[(size_t)r1.x * 32 + p];
        unsigned v2 = h32[(size_t)r2.x * 32 + p];
        unsigned v3 = h32[(size_t)r3.x * 32 + p];
        float g0 = __low2float(*reinterpret_cast<__half2*>(&r0.y));
        float g1 = __low2float(*reinterpret_cast<__half2*>(&r1.y));
        float g2 = __low2float(*reinterpret_cast<__half2*>(&r2.y));
        float g3 = __low2float(*reinterpret_cast<__half2*>(&r3.y));
        float2 f0 = __half22float2(*reinterpret_cast<__half2*>(&v0));
        float2 f1 = __half22float2(*reinterpret_cast<__half2*>(&v1));
        float2 f2 = __half22float2(*reinterpret_cast<__half2*>(&v2));
        float2 f3 = __half22float2(*reinterpret_cast<__half2*>(&v3));
        ax += f0.x * g0; ay += f0.y * g0;
        ax += f1.x * g1; ay += f1.y * g1;
        ax += f2.x * g2; ay += f2.y * g2;
        ax += f3.x * g3; ay += f3.y * g3;
    }
    for (; j < end; ++j) {
        int2 r = csr[j];
        unsigned v = h32[(size_t)r.x * 32 + p];
        float g = __low2float(*reinterpret_cast<__half2*>(&r.y));
        float2 f = __half22float2(*reinterpret_cast<__half2*>(&v));
        ax += f.x * g; ay += f.y * g;
    }
    float2 bb = *(const float2*)&b[2 * p];
    *(float2*)&xs[ln][2 * p] = make_float2(ax + bb.x, ay + bb.y);
    __syncthreads();

    // gemm2: 8 nodes x 40 outs = 320 outputs over 256 threads
    for (int o = tid; o < 8 * OUT_FEATS; o += 256) {
        int node = o / OUT_FEATS, t = o % OUT_FEATS;
        const float* xr = xs[node];
        float acc = 0.f;
#pragma unroll
        for (int k = 0; k < N_HIDDEN; ++k)
            acc += xr[k] * W2[k * OUT_FEATS + t];
        h2[(size_t)(blockIdx.x * 8 + node) * OUT_FEATS + t] = __float2half(acc);
    }
}

// ---------------- agg layer 2 + b2 + log_softmax: 2 nodes per wave ----------------
__global__ __launch_bounds__(256) void agg2_kernel(const __half* __restrict__ h,
                                                   const int* __restrict__ offsets,
                                                   const int2* __restrict__ csr,
                                                   const float* __restrict__ b,
                                                   float* __restrict__ out) {
    const unsigned* h32 = (const unsigned*)h;   // h2 row = 20 dwords
    const int tid = threadIdx.x;
    const int w = tid >> 6, lane = tid & 63;
    const int hf = lane >> 5, p = lane & 31;
    const int n = blockIdx.x * 8 + w * 2 + hf;
    const int pc = (p < 20) ? p : 19;           // clamp: no divergence, no OOB
    int beg = offsets[n], end = offsets[n + 1];

    float ax = 0.f, ay = 0.f;
    int j = beg;
    for (; j + 4 <= end; j += 4) {
        int2 r0 = csr[j + 0], r1 = csr[j + 1], r2 = csr[j + 2], r3 = csr[j + 3];
        unsigned v0 = h32[(size_t)r0.x * 20 + pc];
        unsigned v1 = h32[(size_t)r1.x * 20 + pc];
        unsigned v2 = h32[(size_t)r2.x * 20 + pc];
        unsigned v3 = h32[(size_t)r3.x * 20 + pc];
        float g0 = __high2float(*reinterpret_cast<__half2*>(&r0.y));
        float g1 = __high2float(*reinterpret_cast<__half2*>(&r1.y));
        float g2 = __high2float(*reinterpret_cast<__half2*>(&r2.y));
        float g3 = __high2float(*reinterpret_cast<__half2*>(&r3.y));
        float2 f0 = __half22float2(*reinterpret_cast<__half2*>(&v0));
        float2 f1 = __half22float2(*reinterpret_cast<__half2*>(&v1));
        float2 f2 = __half22float2(*reinterpret_cast<__half2*>(&v2));
        float2 f3 = __half22float2(*reinterpret_cast<__half2*>(&v3));
        ax += f0.x * g0; ay += f0.y * g0;
        ax += f1.x * g1; ay += f1.y * g1;
        ax += f2.x * g2; ay += f2.y * g2;
        ax += f3.x * g3; ay += f3.y * g3;
    }
    for (; j < end; ++j) {
        int2 r = csr[j];
        unsigned v = h32[(size_t)r.x * 20 + pc];
        float g = __high2float(*reinterpret_cast<__half2*>(&r.y));
        float2 f = __half22float2(*reinterpret_cast<__half2*>(&v));
        ax += f.x * g; ay += f.y * g;
    }

    bool valid = (p < 20);
    float vx = valid ? ax + b[2 * p]     : -INFINITY;
    float vy = valid ? ay + b[2 * p + 1] : -INFINITY;
    float m = fmaxf(vx, vy);
#pragma unroll
    for (int off = 16; off; off >>= 1)
        m = fmaxf(m, __shfl_xor(m, off, 32));   // reduce within each 32-lane half
    float ex = valid ? (expf(vx - m) + expf(vy - m)) : 0.f;
#pragma unroll
    for (int off = 16; off; off >>= 1)
        ex += __shfl_xor(ex, off, 32);
    float ls = logf(ex);
    if (valid) {
        float2 o = make_float2(vx - m - ls, vy - m - ls);
        *(float2*)&out[(size_t)n * OUT_FEATS + 2 * p] = o;
    }
}

extern "C" void kernel_launch(void* const* d_in, const int* in_sizes, int n_in,
                              void* d_out, int out_size, void* d_ws, size_t ws_size,
                              hipStream_t stream) {
    const float* features    = (const float*)d_in[0];
    const float* edge_weight = (const float*)d_in[1];
    const int*   src         = (const int*)d_in[2];
    const int*   dst         = (const int*)d_in[3];
    const float* W1          = (const float*)d_in[4];
    const float* b1          = (const float*)d_in[5];
    const float* mu1         = (const float*)d_in[6];
    const float* is1         = (const float*)d_in[7];
    const float* W2          = (const float*)d_in[8];
    const float* b2          = (const float*)d_in[9];
    const float* mu2         = (const float*)d_in[10];
    const float* is2         = (const float*)d_in[11];
    float* out = (float*)d_out;

    // Workspace: csr int2[800k] | tmp int2[800k] | h1 half[3.2M] | h2 half[2M]
    //            | counts[50k] | partials[256] | cursor[50k] | offsets[50k+1]
    int2*   csr     = (int2*)d_ws;
    int2*   tmp     = csr + N_EDGES;
    __half* h1      = (__half*)(tmp + N_EDGES);
    __half* h2      = h1 + (size_t)N_NODES * N_HIDDEN;
    int*    counts  = (int*)(h2 + (size_t)N_NODES * OUT_FEATS);
    int*    partials= counts + N_NODES;          // 256 slots (196 used)
    int*    cursor  = partials + 256;
    int*    offsets = cursor + N_NODES;

    hipMemsetAsync(counts, 0, (N_NODES + 256) * sizeof(int), stream);

    edge_kernel<<<(N_EDGES + 255) / 256, 256, 0, stream>>>(
        src, dst, edge_weight, mu1, is1, mu2, is2, counts, tmp);

    scan_kernel<<<SCAN_NB, 256, 0, stream>>>(counts, offsets, cursor, partials);

    fillgemm_kernel<<<GT_TILES + FILL_NB, 256, 0, stream>>>(
        features, W1, dst, tmp, cursor, csr, h1);

    agg1_gemm2_kernel<<<N_NODES / 8, 256, 0, stream>>>(h1, offsets, csr, b1, W2, h2);

    agg2_kernel<<<N_NODES / 8, 256, 0, stream>>>(h2, offsets, csr, b2, out);
}

// Round 14
// 261.664 us; speedup vs baseline: 1.2667x; 1.0276x over previous
//
#include <hip/hip_runtime.h>
#include <hip/hip_fp16.h>
#include <math.h>

#define N_NODES 50000
#define N_EDGES 800000
#define IN_FEATS 128
#define N_HIDDEN 64
#define OUT_FEATS 40
#define DIM 8
#define SCAN_NB ((N_NODES + 255) / 256)       // 196
#define GT_TILES ((N_NODES + 63) / 64)        // 782 gemm tiles
#define FILL_NB 1024

typedef _Float16 half8 __attribute__((ext_vector_type(8)));
typedef float floatx4 __attribute__((ext_vector_type(4)));

// ---------------- wave-wide inclusive scan (64 lanes) ----------------
__device__ __forceinline__ int wave_incl_scan(int x, int lane) {
#pragma unroll
    for (int off = 1; off < 64; off <<= 1) {
        int v = __shfl_up(x, off, 64);
        if (lane >= off) x += v;
    }
    return x;
}

// ============================================================================
// K1: in-degree histogram only. int4 loads, 4 edges/thread.
// ============================================================================
__global__ __launch_bounds__(256) void hist_kernel(const int* __restrict__ dst,
                                                   int* __restrict__ counts) {
    int i = blockIdx.x * 256 + threadIdx.x;      // quad index
    if (i * 4 >= N_EDGES) return;
    int4 d = ((const int4*)dst)[i];
    atomicAdd(&counts[d.x], 1);
    atomicAdd(&counts[d.y], 1);
    atomicAdd(&counts[d.z], 1);
    atomicAdd(&counts[d.w], 1);
}

// ============================================================================
// K2: single-dispatch decoupled-lookback scan: counts -> offsets + cursor.
// ============================================================================
__global__ __launch_bounds__(256) void scan_kernel(const int* __restrict__ counts,
                                                   int* __restrict__ offsets,
                                                   int* __restrict__ cursor,
                                                   int* __restrict__ partials) {
    const int tid = threadIdx.x, bid = blockIdx.x;
    int i = bid * 256 + tid;
    int lane = tid & 63, wid = tid >> 6;
    int x = (i < N_NODES) ? counts[i] : 0;
    int incl = wave_incl_scan(x, lane);
    __shared__ int wsum[4];
    __shared__ int sExc, sTot;
    if (lane == 63) wsum[wid] = incl;
    __syncthreads();
    int base = 0;
#pragma unroll
    for (int w = 0; w < 4; ++w)
        if (w < wid) base += wsum[w];
    int lexcl = base + incl - x;
    if (tid == 255) sTot = base + incl;
    __syncthreads();
    if (tid == 0) {
        int T = sTot;
        if (bid == 0) {
            __hip_atomic_store(&partials[0], (T << 2) | 2,
                               __ATOMIC_RELAXED, __HIP_MEMORY_SCOPE_AGENT);
            sExc = 0;
        } else {
            __hip_atomic_store(&partials[bid], (T << 2) | 1,
                               __ATOMIC_RELAXED, __HIP_MEMORY_SCOPE_AGENT);
            int sum = 0, pb = bid - 1;
            while (true) {
                int v = __hip_atomic_load(&partials[pb],
                                          __ATOMIC_RELAXED, __HIP_MEMORY_SCOPE_AGENT);
                if (v == 0) continue;
                sum += v >> 2;
                if ((v & 3) == 2) break;
                --pb;
            }
            __hip_atomic_store(&partials[bid], ((sum + T) << 2) | 2,
                               __ATOMIC_RELAXED, __HIP_MEMORY_SCOPE_AGENT);
            sExc = sum;
        }
    }
    __syncthreads();
    int E = sExc;
    if (i < N_NODES) {
        int v = E + lexcl;
        offsets[i] = v;
        cursor[i]  = v;
    }
    if (bid == SCAN_NB - 1 && tid == 0) offsets[N_NODES] = N_EDGES;
}

// ============================================================================
// K3: gemm1 MFMA tiles (blocks < GT_TILES) + CSR fill w/ inline gaussian
// (remaining blocks). Gaussian VALU + ew reads hide under scatter write stalls.
// ============================================================================
__global__ __launch_bounds__(256) void fillgemm_kernel(
    const float* __restrict__ features, const float* __restrict__ W1,
    const int* __restrict__ src, const int* __restrict__ dst,
    const float* __restrict__ ew,
    const float* __restrict__ mu1, const float* __restrict__ is1,
    const float* __restrict__ mu2, const float* __restrict__ is2,
    int* __restrict__ cursor, int2* __restrict__ csr,
    __half* __restrict__ h1)
{
    const int tid = threadIdx.x;
    __shared__ __align__(16) __half WT[64][136];   // W1^T fp16, 17.4 KB

    if (blockIdx.x >= GT_TILES) {
        // ---- fill half: gaussian inline + scatter packed record ----
        int fb = blockIdx.x - GT_TILES;
        for (int e = fb * 256 + tid; e < N_EDGES; e += FILL_NB * 256) {
            const float4* ew4 = (const float4*)(ew + (size_t)e * DIM);
            float4 wa = ew4[0], wb = ew4[1];
            float v[8] = {wa.x, wa.y, wa.z, wa.w, wb.x, wb.y, wb.z, wb.w};
            float s1 = 0.f, s2 = 0.f;
#pragma unroll
            for (int d = 0; d < DIM; ++d) {
                float d1 = v[d] - mu1[d]; float a1 = is1[d];
                float d2 = v[d] - mu2[d]; float a2 = is2[d];
                s1 += d1 * d1 * a1 * a1;
                s2 += d2 * d2 * a2 * a2;
            }
            __half2 g = __floats2half2_rn(expf(-0.5f * s1), expf(-0.5f * s2));
            int2 rec;
            rec.x = src[e];
            rec.y = *reinterpret_cast<int*>(&g);
            int pos = atomicAdd(&cursor[dst[e]], 1);
            csr[pos] = rec;
        }
        return;
    }

    // ---- gemm1 tile: 64 nodes x 64 feats, MFMA 16x16x32 f16, A from global ----
    int nodeBase = blockIdx.x * 64;
    for (int rep = 0; rep < 32; ++rep) {
        int idx = tid + rep * 256;          // 0..8191 = k*64 + n
        int k = idx >> 6, n = idx & 63;
        WT[n][k] = __float2half(W1[idx]);
    }
    __syncthreads();

    int lane = tid & 63, w = tid >> 6;
    int m = lane & 15, quad = lane >> 4;
    int row = nodeBase + w * 16 + m;
    int rowc = (row < N_NODES) ? row : (N_NODES - 1);
    const float* fr = features + (size_t)rowc * IN_FEATS;

    floatx4 acc0 = {0.f,0.f,0.f,0.f}, acc1 = acc0, acc2 = acc0, acc3 = acc0;
#pragma unroll
    for (int kc = 0; kc < 4; ++kc) {
        float4 fa = *(const float4*)(fr + kc * 32 + quad * 8);
        float4 fb = *(const float4*)(fr + kc * 32 + quad * 8 + 4);
        union { half8 v; __half2 h2[4]; } A;
        A.h2[0] = __floats2half2_rn(fa.x, fa.y);
        A.h2[1] = __floats2half2_rn(fa.z, fa.w);
        A.h2[2] = __floats2half2_rn(fb.x, fb.y);
        A.h2[3] = __floats2half2_rn(fb.z, fb.w);
        half8 b0 = *(const half8*)&WT[ 0 + m][kc * 32 + quad * 8];
        half8 b1 = *(const half8*)&WT[16 + m][kc * 32 + quad * 8];
        half8 b2 = *(const half8*)&WT[32 + m][kc * 32 + quad * 8];
        half8 b3 = *(const half8*)&WT[48 + m][kc * 32 + quad * 8];
        acc0 = __builtin_amdgcn_mfma_f32_16x16x32_f16(A.v, b0, acc0, 0, 0, 0);
        acc1 = __builtin_amdgcn_mfma_f32_16x16x32_f16(A.v, b1, acc1, 0, 0, 0);
        acc2 = __builtin_amdgcn_mfma_f32_16x16x32_f16(A.v, b2, acc2, 0, 0, 0);
        acc3 = __builtin_amdgcn_mfma_f32_16x16x32_f16(A.v, b3, acc3, 0, 0, 0);
    }
    int nodeRow = nodeBase + w * 16 + quad * 4;
#pragma unroll
    for (int r = 0; r < 4; ++r) {
        int n = nodeRow + r;
        if (n < N_NODES) {
            size_t base = (size_t)n * N_HIDDEN + m;
            h1[base +  0] = __float2half(acc0[r]);
            h1[base + 16] = __float2half(acc1[r]);
            h1[base + 32] = __float2half(acc2[r]);
            h1[base + 48] = __float2half(acc3[r]);
        }
    }
}

// ---------------- agg1 + gemm2 fused: 2 nodes per wave, packed fp16 pairs ----------
__global__ __launch_bounds__(256) void agg1_gemm2_kernel(const __half* __restrict__ h,
                                                         const int* __restrict__ offsets,
                                                         const int2* __restrict__ csr,
                                                         const float* __restrict__ b,
                                                         const float* __restrict__ W2,
                                                         __half* __restrict__ h2) {
    __shared__ float xs[8][64];
    const unsigned* h32 = (const unsigned*)h;   // h1 row = 32 dwords
    const int tid = threadIdx.x;
    const int w = tid >> 6, lane = tid & 63;
    const int hf = lane >> 5, p = lane & 31;
    const int ln = w * 2 + hf;                  // local node 0..7
    const int n = blockIdx.x * 8 + ln;
    int beg = offsets[n], end = offsets[n + 1];

    float ax = 0.f, ay = 0.f;
    int j = beg;
    for (; j + 4 <= end; j += 4) {
        int2 r0 = csr[j + 0], r1 = csr[j + 1], r2 = csr[j + 2], r3 = csr[j + 3];
        unsigned v0 = h32[(size_t)r0.x * 32 + p];
        unsigned v1 = h32[(size_t)r1.x * 32 + p];
        unsigned v2 = h32[(size_t)r2.x * 32 + p];
        unsigned v3 = h32[(size_t)r3.x * 32 + p];
        float g0 = __low2float(*reinterpret_cast<__half2*>(&r0.y));
        float g1 = __low2float(*reinterpret_cast<__half2*>(&r1.y));
        float g2 = __low2float(*reinterpret_cast<__half2*>(&r2.y));
        float g3 = __low2float(*reinterpret_cast<__half2*>(&r3.y));
        float2 f0 = __half22float2(*reinterpret_cast<__half2*>(&v0));
        float2 f1 = __half22float2(*reinterpret_cast<__half2*>(&v1));
        float2 f2 = __half22float2(*reinterpret_cast<__half2*>(&v2));
        float2 f3 = __half22float2(*reinterpret_cast<__half2*>(&v3));
        ax += f0.x * g0; ay += f0.y * g0;
        ax += f1.x * g1; ay += f1.y * g1;
        ax += f2.x * g2; ay += f2.y * g2;
        ax += f3.x * g3; ay += f3.y * g3;
    }
    for (; j < end; ++j) {
        int2 r = csr[j];
        unsigned v = h32[(size_t)r.x * 32 + p];
        float g = __low2float(*reinterpret_cast<__half2*>(&r.y));
        float2 f = __half22float2(*reinterpret_cast<__half2*>(&v));
        ax += f.x * g; ay += f.y * g;
    }
    float2 bb = *(const float2*)&b[2 * p];
    *(float2*)&xs[ln][2 * p] = make_float2(ax + bb.x, ay + bb.y);
    __syncthreads();

    // gemm2: 8 nodes x 40 outs = 320 outputs over 256 threads
    for (int o = tid; o < 8 * OUT_FEATS; o += 256) {
        int node = o / OUT_FEATS, t = o % OUT_FEATS;
        const float* xr = xs[node];
        float acc = 0.f;
#pragma unroll
        for (int k = 0; k < N_HIDDEN; ++k)
            acc += xr[k] * W2[k * OUT_FEATS + t];
        h2[(size_t)(blockIdx.x * 8 + node) * OUT_FEATS + t] = __float2half(acc);
    }
}

// ---------------- agg layer 2 + b2 + log_softmax: 2 nodes per wave ----------------
__global__ __launch_bounds__(256) void agg2_kernel(const __half* __restrict__ h,
                                                   const int* __restrict__ offsets,
                                                   const int2* __restrict__ csr,
                                                   const float* __restrict__ b,
                                                   float* __restrict__ out) {
    const unsigned* h32 = (const unsigned*)h;   // h2 row = 20 dwords
    const int tid = threadIdx.x;
    const int w = tid >> 6, lane = tid & 63;
    const int hf = lane >> 5, p = lane & 31;
    const int n = blockIdx.x * 8 + w * 2 + hf;
    const int pc = (p < 20) ? p : 19;           // clamp: no divergence, no OOB
    int beg = offsets[n], end = offsets[n + 1];

    float ax = 0.f, ay = 0.f;
    int j = beg;
    for (; j + 4 <= end; j += 4) {
        int2 r0 = csr[j + 0], r1 = csr[j + 1], r2 = csr[j + 2], r3 = csr[j + 3];
        unsigned v0 = h32[(size_t)r0.x * 20 + pc];
        unsigned v1 = h32[(size_t)r1.x * 20 + pc];
        unsigned v2 = h32[(size_t)r2.x * 20 + pc];
        unsigned v3 = h32[(size_t)r3.x * 20 + pc];
        float g0 = __high2float(*reinterpret_cast<__half2*>(&r0.y));
        float g1 = __high2float(*reinterpret_cast<__half2*>(&r1.y));
        float g2 = __high2float(*reinterpret_cast<__half2*>(&r2.y));
        float g3 = __high2float(*reinterpret_cast<__half2*>(&r3.y));
        float2 f0 = __half22float2(*reinterpret_cast<__half2*>(&v0));
        float2 f1 = __half22float2(*reinterpret_cast<__half2*>(&v1));
        float2 f2 = __half22float2(*reinterpret_cast<__half2*>(&v2));
        float2 f3 = __half22float2(*reinterpret_cast<__half2*>(&v3));
        ax += f0.x * g0; ay += f0.y * g0;
        ax += f1.x * g1; ay += f1.y * g1;
        ax += f2.x * g2; ay += f2.y * g2;
        ax += f3.x * g3; ay += f3.y * g3;
    }
    for (; j < end; ++j) {
        int2 r = csr[j];
        unsigned v = h32[(size_t)r.x * 20 + pc];
        float g = __high2float(*reinterpret_cast<__half2*>(&r.y));
        float2 f = __half22float2(*reinterpret_cast<__half2*>(&v));
        ax += f.x * g; ay += f.y * g;
    }

    bool valid = (p < 20);
    float vx = valid ? ax + b[2 * p]     : -INFINITY;
    float vy = valid ? ay + b[2 * p + 1] : -INFINITY;
    float m = fmaxf(vx, vy);
#pragma unroll
    for (int off = 16; off; off >>= 1)
        m = fmaxf(m, __shfl_xor(m, off, 32));   // reduce within each 32-lane half
    float ex = valid ? (expf(vx - m) + expf(vy - m)) : 0.f;
#pragma unroll
    for (int off = 16; off; off >>= 1)
        ex += __shfl_xor(ex, off, 32);
    float ls = logf(ex);
    if (valid) {
        float2 o = make_float2(vx - m - ls, vy - m - ls);
        *(float2*)&out[(size_t)n * OUT_FEATS + 2 * p] = o;
    }
}

extern "C" void kernel_launch(void* const* d_in, const int* in_sizes, int n_in,
                              void* d_out, int out_size, void* d_ws, size_t ws_size,
                              hipStream_t stream) {
    const float* features    = (const float*)d_in[0];
    const float* edge_weight = (const float*)d_in[1];
    const int*   src         = (const int*)d_in[2];
    const int*   dst         = (const int*)d_in[3];
    const float* W1          = (const float*)d_in[4];
    const float* b1          = (const float*)d_in[5];
    const float* mu1         = (const float*)d_in[6];
    const float* is1         = (const float*)d_in[7];
    const float* W2          = (const float*)d_in[8];
    const float* b2          = (const float*)d_in[9];
    const float* mu2         = (const float*)d_in[10];
    const float* is2         = (const float*)d_in[11];
    float* out = (float*)d_out;

    // Workspace: csr int2[800k] | h1 half[3.2M] | h2 half[2M]
    //            | counts[50k] | partials[256] | cursor[50k] | offsets[50k+1]
    int2*   csr     = (int2*)d_ws;
    __half* h1      = (__half*)(csr + N_EDGES);
    __half* h2      = h1 + (size_t)N_NODES * N_HIDDEN;
    int*    counts  = (int*)(h2 + (size_t)N_NODES * OUT_FEATS);
    int*    partials= counts + N_NODES;          // 256 slots (196 used)
    int*    cursor  = partials + 256;
    int*    offsets = cursor + N_NODES;

    hipMemsetAsync(counts, 0, (N_NODES + 256) * sizeof(int), stream);

    hist_kernel<<<(N_EDGES / 4 + 255) / 256, 256, 0, stream>>>(dst, counts);

    scan_kernel<<<SCAN_NB, 256, 0, stream>>>(counts, offsets, cursor, partials);

    fillgemm_kernel<<<GT_TILES + FILL_NB, 256, 0, stream>>>(
        features, W1, src, dst, edge_weight, mu1, is1, mu2, is2, cursor, csr, h1);

    agg1_gemm2_kernel<<<N_NODES / 8, 256, 0, stream>>>(h1, offsets, csr, b1, W2, h2);

    agg2_kernel<<<N_NODES / 8, 256, 0, stream>>>(h2, offsets, csr, b2, out);
}